// Round 15
// baseline (3102.880 us; speedup 1.0000x reference)
//
#include <hip/hip_runtime.h>
#include <stdint.h>
#include <stddef.h>

// Reverse LSTM: T=256, B=64, D=H=1024.
// R15 = R14 (proven regular-launch persistent kernel) + per-quarter dataflow:
//   - per-WAVE publish + flag (4 atomicAdds/WG/step, lim = 4*si); HXu staging is
//     wave-local so only 2 barriers/step remain (cross-wave ordering comes
//     transitively from the spins).
//   - per-quarter gating: flag loads (sc0 sc1) threaded into the counted-vmcnt
//     pipeline; each quarter's h loads issue right after its 16 producer flags
//     pass. All waits are drain-history-invariant ("all but newest N").
//   - ys(prev) stores issued inside the load pipeline (acks overlap MALL loads).

typedef unsigned short u16;
typedef __attribute__((ext_vector_type(4))) unsigned short u16x4;
typedef __attribute__((ext_vector_type(8))) short short8;
typedef __attribute__((ext_vector_type(4))) float f32x4;

#define T_LEN 256
#define YS_ELEMS (256 * 64 * 1024)  // 16777216

__device__ __forceinline__ u16 f2bf(float f) {
  union { float f; unsigned int i; } v; v.f = f;
  unsigned int r = v.i + 0x7FFFu + ((v.i >> 16) & 1u);  // RNE
  return (u16)(r >> 16);
}
__device__ __forceinline__ float bf2f(u16 u) {
  union { unsigned int i; float f; } v; v.i = ((unsigned int)u) << 16; return v.f;
}
__device__ __forceinline__ void gload_lds16(const void* g, void* l) {
  __builtin_amdgcn_global_load_lds(
      (const __attribute__((address_space(1))) unsigned int*)g,
      (__attribute__((address_space(3))) unsigned int*)l, 16, 0, 0);
}
__device__ __forceinline__ float sigm_fast(float x) { return 1.f / (1.f + __expf(-x)); }

// plain CACHED 16B load with compile-time byte offset (no wait; counted vmcnt)
#define ISSUE_LD16C(dst, ptr, off)                                      \
  asm volatile("global_load_dwordx4 %0, %1, off offset:%c2"             \
               : "=v"(dst) : "v"(ptr), "i"(off) : "memory")

// plain cached 8B load (vmcnt-ordered among our asm ops)
#define LD8_PLAIN(dst, ptr)                                             \
  asm volatile("global_load_dwordx2 %0, %1, off"                        \
               : "=v"(dst) : "v"(ptr) : "memory")

// device-coherent 8B write-through store (to MALL home)
#define ST8_WT(ptr, val)                                                \
  asm volatile("global_store_dwordx2 %0, %1, off sc0 sc1"               \
               :: "v"(ptr), "v"(val) : "memory")

// device-coherent 4B flag load (bypass L1/L2; counted, no implicit wait)
#define CHK_ISSUE(dst, qi)                                              \
  asm volatile("global_load_dword %0, %1, off sc0 sc1"                  \
               : "=v"(dst) : "v"(flags + ((((qi) * 16 + flid)) << 5)) : "memory")

#define WAIT_VMN(n) do { asm volatile("s_waitcnt vmcnt(" #n ")" ::: "memory"); \
                         __builtin_amdgcn_sched_barrier(0); } while (0)

// spin: fast path = register test only; slow path re-issues the flag load
#define SPIN_Q(fq, qi) do {                                              \
    while (!__all(fq >= lim)) {                                          \
      __builtin_amdgcn_s_sleep(1);                                       \
      CHK_ISSUE(fq, qi);                                                 \
      WAIT_VMN(0);                                                       \
    }                                                                    \
  } while (0)

// ---------------- Phase 0 ----------------
__global__ void cast_f32_bf16(const float* __restrict__ src, u16* __restrict__ dst, int n4) {
  int i = blockIdx.x * blockDim.x + threadIdx.x;
  const int stride = gridDim.x * blockDim.x;
  for (; i < n4; i += stride) {
    float4 v = ((const float4*)src)[i];
    u16x4 o;
    o[0] = f2bf(v.x); o[1] = f2bf(v.y); o[2] = f2bf(v.z); o[3] = f2bf(v.w);
    ((u16x4*)dst)[i] = o;
  }
}

// diagnostic canary: out[0] = 100 (lstm_rec overwrites it at si=255)
__global__ void canary_k(float* __restrict__ out) { out[0] = 100.0f; }

// ---------------- Phase 1: pregate GEMM (proven, unchanged) ----------------
__global__ __launch_bounds__(256, 2) void gemm_pre(
    const u16* __restrict__ X, const u16* __restrict__ Wih,
    const float* __restrict__ bih, const float* __restrict__ bhh,
    u16* __restrict__ Pout)
{
  __shared__ u16 As[128 * 64];
  __shared__ u16 Bs[128 * 64];
  const int tid = threadIdx.x;
  const int lane = tid & 63;
  const int wid = tid >> 6;
  const int wm = wid & 1, wn = wid >> 1;
  const int Mt = blockIdx.x, Nt = blockIdx.y;

  f32x4 acc[4][4] = {};
  const int rsub = lane >> 3;
  const int src_chunk = (lane & 7) ^ rsub;

  for (int it = 0; it < 16; ++it) {
    const int k0 = it * 64;
    #pragma unroll
    for (int q = 0; q < 4; ++q) {
      const int j = wid * 4 + q;
      const int row_local = j * 8 + rsub;
      const u16* ga = X   + ((size_t)(Mt * 128 + row_local)) * 1024 + k0 + src_chunk * 8;
      const u16* gb = Wih + ((size_t)(Nt * 128 + row_local)) * 1024 + k0 + src_chunk * 8;
      gload_lds16(ga, (char*)As + j * 1024);
      gload_lds16(gb, (char*)Bs + j * 1024);
    }
    __syncthreads();
    #pragma unroll
    for (int ks = 0; ks < 2; ++ks) {
      short8 af[4], bfv[4];
      #pragma unroll
      for (int f = 0; f < 4; ++f) {
        const int ra = wm * 64 + f * 16 + (lane & 15);
        const int rb = wn * 64 + f * 16 + (lane & 15);
        const int kc = ks * 4 + (lane >> 4);
        af[f]  = *(const short8*)((const char*)As + ra * 128 + ((kc ^ (ra & 7)) << 4));
        bfv[f] = *(const short8*)((const char*)Bs + rb * 128 + ((kc ^ (rb & 7)) << 4));
      }
      #pragma unroll
      for (int fm = 0; fm < 4; ++fm)
        #pragma unroll
        for (int fn = 0; fn < 4; ++fn)
          acc[fm][fn] = __builtin_amdgcn_mfma_f32_16x16x32_bf16(af[fm], bfv[fn], acc[fm][fn], 0, 0, 0);
    }
    __syncthreads();
  }

  const int t_out = Mt * 2 + wm;
  #pragma unroll
  for (int fn = 0; fn < 4; ++fn) {
    const int n = Nt * 128 + wn * 64 + fn * 16 + (lane & 15);
    const float bias = bih[n] + bhh[n];
    #pragma unroll
    for (int fm = 0; fm < 4; ++fm) {
      const int b = fm * 16 + ((lane >> 4) << 2);
      u16x4 o;
      #pragma unroll
      for (int r = 0; r < 4; ++r) o[r] = f2bf(acc[fm][fn][r] + bias);
      *(u16x4*)(Pout + ((size_t)t_out * 4096 + n) * 64 + b) = o;
    }
  }
}

// ---------------- Phase 2: persistent recurrence ----------------
// Static LDS = 131072 + 16384 = 147456 B. Regular launch, 64 WGs (co-resident).
__global__ __launch_bounds__(256, 1) void lstm_rec(
    const u16* __restrict__ P, const float* __restrict__ c0,
    const float* __restrict__ Whh, u16* __restrict__ ring,
    float* __restrict__ out, int* __restrict__ flags)
{
  __shared__ u16 Ws[64 * 1024];
  __shared__ float GX[4096];     // gate exchange; first 2KB reused as HXu

  const int tid = threadIdx.x;
  const int lane = tid & 63;
  const int wid = tid >> 6;
  const int wg = blockIdx.x;

  // one-time W_hh slice -> LDS (bf16, XOR-swizzled rows)  [R14 verbatim]
  {
    const int rowp = tid >> 2;
    const int q = tid & 3;
    const int grow = (rowp >> 4) * 1024 + wg * 16 + (rowp & 15);
    const float4* src = (const float4*)(Whh + (size_t)grow * 1024 + q * 256);
    #pragma unroll 2
    for (int j = 0; j < 32; ++j) {
      float4 v0 = src[j * 2];
      float4 v1 = src[j * 2 + 1];
      short8 pk;
      pk[0] = (short)f2bf(v0.x); pk[1] = (short)f2bf(v0.y);
      pk[2] = (short)f2bf(v0.z); pk[3] = (short)f2bf(v0.w);
      pk[4] = (short)f2bf(v1.x); pk[5] = (short)f2bf(v1.y);
      pk[6] = (short)f2bf(v1.z); pk[7] = (short)f2bf(v1.w);
      const int kc = q * 32 + j;
      *(short8*)((char*)Ws + rowp * 2048 + ((kc ^ (rowp & 7)) << 4)) = pk;
    }
  }

  // pointwise role: unit u, batches b0..b0+3  [R14 verbatim]
  const int u = tid & 15;
  const int b0 = (tid >> 4) << 2;
  const int jh = wg * 16 + u;
  float cs[4];
  #pragma unroll
  for (int r = 0; r < 4; ++r) cs[r] = c0[(size_t)(b0 + r) * 1024 + jh];

  // h-publish role (wave-local rows): row srow, 8B chunk sq
  const int srow = tid >> 2;
  const int sq = tid & 3;

  const int wm = wid & 1;
  const int wn = wid >> 1;
  const int flid = lane & 15;

  u16* HXu = (u16*)GX;

  __syncthreads();

  #define ISSUE_Q(buf, qi) {                                                   \
    _Pragma("unroll")                                                          \
    for (int kq_ = 0; kq_ < 8; ++kq_) {                                        \
      ISSUE_LD16C(buf[kq_][0], pA0, (qi) * 512 + kq_ * 64);                    \
      ISSUE_LD16C(buf[kq_][1], pA1, (qi) * 512 + kq_ * 64);                    \
    } }

  #define MFMA_Q(buf, qi) {                                                    \
    _Pragma("unroll")                                                          \
    for (int kq_ = 0; kq_ < 8; ++kq_) {                                        \
      const int kabs_ = (qi) * 8 + kq_;                                        \
      _Pragma("unroll")                                                        \
      for (int ni_ = 0; ni_ < 2; ++ni_) {                                      \
        const int rs_ = wn * 32 + ni_ * 16 + (lane & 15);                      \
        const int kcl_ = kabs_ * 4 + (lane >> 4);                              \
        const short8 bfr_ = *(const short8*)((const char*)Ws + rs_ * 2048      \
                            + ((kcl_ ^ (rs_ & 7)) << 4));                      \
        acc[0][ni_] = __builtin_amdgcn_mfma_f32_16x16x32_bf16(buf[kq_][0], bfr_, acc[0][ni_], 0, 0, 0); \
        acc[1][ni_] = __builtin_amdgcn_mfma_f32_16x16x32_bf16(buf[kq_][1], bfr_, acc[1][ni_], 0, 0, 0); \
      } } }

  float hprev[4];

  for (int si = 0; si < 256; ++si) {
    const int t = 255 - si;
    const int lim = si * 4;
    const u16* rb = ring + (size_t)si * 65536;

    const u16* pA0 = rb + (size_t)(wm * 32 +  0 + (lane & 15)) * 1024 + ((lane >> 4) << 3);
    const u16* pA1 = rb + (size_t)(wm * 32 + 16 + (lane & 15)) * 1024 + ((lane >> 4) << 3);

    // flag snapshot (oldest), then P loads (newest-4)
    int f0, f1, f2, f3;
    CHK_ISSUE(f0, 0); CHK_ISSUE(f1, 1); CHK_ISSUE(f2, 2); CHK_ISSUE(f3, 3);
    const size_t pbase = (size_t)t * 262144;
    unsigned long long Pi, Pf, Pg, Po;
    LD8_PLAIN(Pi, P + pbase + (size_t)(0 * 1024 + jh) * 64 + b0);
    LD8_PLAIN(Pf, P + pbase + (size_t)(1 * 1024 + jh) * 64 + b0);
    LD8_PLAIN(Pg, P + pbase + (size_t)(2 * 1024 + jh) * 64 + b0);
    LD8_PLAIN(Po, P + pbase + (size_t)(3 * 1024 + jh) * 64 + b0);
    WAIT_VMN(4);          // all but P retired => flag snapshot valid

    f32x4 acc[2][2] = {};
    short8 afrA[8][2], afrB[8][2];

    // per-quarter gated counted pipeline (all waits younger-count invariant)
    SPIN_Q(f0, 0);
    ISSUE_Q(afrA, 0)
    SPIN_Q(f1, 1);
    ISSUE_Q(afrB, 1)
    // ys(prev): HBM acks overlap q0/q1 MALL load latency
    if (si > 0) {
      #pragma unroll
      for (int r = 0; r < 4; ++r)
        out[((size_t)(t + 1) * 64 + b0 + r) * 1024 + jh] = hprev[r];
    }
    WAIT_VMN(16); MFMA_Q(afrA, 0)    // q0 retired (ys/q1 newest)
    SPIN_Q(f2, 2);
    ISSUE_Q(afrA, 2)
    WAIT_VMN(16); MFMA_Q(afrB, 1)    // newest16 = q2
    SPIN_Q(f3, 3);
    ISSUE_Q(afrB, 3)
    WAIT_VMN(16); MFMA_Q(afrA, 2)    // newest16 = q3
    WAIT_VMN(0);  MFMA_Q(afrB, 3)

    // gate exchange through LDS  [R14 verbatim]
    #pragma unroll
    for (int mi = 0; mi < 2; ++mi)
      #pragma unroll
      for (int ni = 0; ni < 2; ++ni) {
        const int g = wn * 2 + ni;
        const int uu = lane & 15;
        const int bb = wm * 32 + mi * 16 + ((lane >> 4) << 2);
        *(f32x4*)((char*)GX + ((((g * 16 + uu) * 64 + bb) << 2) ^ ((uu & 7) << 4))) = acc[mi][ni];
      }
    __syncthreads();

    const f32x4 vi = *(const f32x4*)((char*)GX + ((((0 * 16 + u) * 64 + b0) << 2) ^ ((u & 7) << 4)));
    const f32x4 vf = *(const f32x4*)((char*)GX + ((((1 * 16 + u) * 64 + b0) << 2) ^ ((u & 7) << 4)));
    const f32x4 vg = *(const f32x4*)((char*)GX + ((((2 * 16 + u) * 64 + b0) << 2) ^ ((u & 7) << 4)));
    const f32x4 vo = *(const f32x4*)((char*)GX + ((((3 * 16 + u) * 64 + b0) << 2) ^ ((u & 7) << 4)));

    float hvv[4], cnn[4];
    #pragma unroll
    for (int r = 0; r < 4; ++r) {
      const float xi = vi[r] + bf2f((u16)(Pi >> (16 * r)));
      const float xf = vf[r] + bf2f((u16)(Pf >> (16 * r)));
      const float xg = vg[r] + bf2f((u16)(Pg >> (16 * r)));
      const float xo = vo[r] + bf2f((u16)(Po >> (16 * r)));
      const float ig = sigm_fast(xi);
      const float fg = sigm_fast(xf);
      const float og = sigm_fast(xo);
      const float cn = fg * cs[r] + ig * tanhf(xg);
      const float hv = og * tanhf(cn);
      cs[r] = cn; cnn[r] = cn; hvv[r] = hv;
    }

    if (si < 255) {
      __syncthreads();   // all waves' GX pointwise reads done -> reuse as HXu
      #pragma unroll
      for (int r = 0; r < 4; ++r) HXu[(b0 + r) * 16 + u] = f2bf(hvv[r]);  // wave-local rows
      asm volatile("s_waitcnt lgkmcnt(0)" ::: "memory");
      __builtin_amdgcn_sched_barrier(0);
      {
        u16* wb = ring + (size_t)(si + 1) * 65536;
        const unsigned long long hv8 = *(const unsigned long long*)(HXu + srow * 16 + sq * 4);
        ST8_WT(wb + (size_t)srow * 1024 + wg * 16 + sq * 4, hv8);
      }
      WAIT_VMN(0);       // this WAVE's 512B publish performed at MALL
      if (lane == 0) atomicAdd(&flags[wg << 5], 1);   // per-wave flag (+4/WG/step)
      // no trailing barrier: next-step spins order cross-wave hazards
      // (a wave's own-quarter spin requires all 4 of its WG's wave-flags)
    } else {
      #pragma unroll
      for (int r = 0; r < 4; ++r) {
        out[((size_t)t * 64 + b0 + r) * 1024 + jh] = hvv[r];            // ys t=0
        out[YS_ELEMS + (size_t)(b0 + r) * 1024 + jh] = hvv[r];          // hT
        out[YS_ELEMS + 65536 + (size_t)(b0 + r) * 1024 + jh] = cnn[r];  // cT
      }
    }
    #pragma unroll
    for (int r = 0; r < 4; ++r) hprev[r] = hvv[r];
  }
  #undef ISSUE_Q
  #undef MFMA_Q
}

// ---------------- launch ----------------
extern "C" void kernel_launch(void* const* d_in, const int* in_sizes, int n_in,
                              void* d_out, int out_size, void* d_ws, size_t ws_size,
                              hipStream_t stream) {
  const float* x   = (const float*)d_in[0];
  const float* h0  = (const float*)d_in[1];
  const float* c0  = (const float*)d_in[2];
  const float* Wih = (const float*)d_in[3];
  const float* Whh = (const float*)d_in[4];
  const float* bih = (const float*)d_in[5];
  const float* bhh = (const float*)d_in[6];
  float* out = (float*)d_out;

  char* ws = (char*)d_ws;
  u16* x_bf   = (u16*)(ws + 0);           // 32MB; recycled as h ring after gemm_pre
  u16* ring   = (u16*)(ws + 0);           // 256 x 131072 B
  u16* wih_bf = (u16*)(ws + 33554432);
  u16* Pp     = (u16*)(ws + 41943040);    // 128MB
  int* flags  = (int*)(ws + 176160768);   // 8KB (64 flags, 128B-padded)

  hipLaunchKernelGGL(cast_f32_bf16, dim3(2048), dim3(256), 0, stream, x,   x_bf,   4194304);
  hipLaunchKernelGGL(cast_f32_bf16, dim3(1024), dim3(256), 0, stream, Wih, wih_bf, 1048576);
  hipLaunchKernelGGL(gemm_pre, dim3(128, 32), dim3(256), 0, stream, x_bf, wih_bf, bih, bhh, Pp);
  hipMemsetAsync(flags, 0, 8192, stream);
  hipLaunchKernelGGL(cast_f32_bf16, dim3(64), dim3(256), 0, stream, h0, ring, 16384);
  hipLaunchKernelGGL(canary_k, dim3(1), dim3(1), 0, stream, out);

  // REGULAR launch (not cooperative): 64 WGs, 1/CU -> trivially co-resident.
  hipLaunchKernelGGL(lstm_rec, dim3(64), dim3(256), 0, stream,
                     (const u16*)Pp, c0, Whh, ring, out, flags);
}

// Round 16
// 1812.392 us; speedup vs baseline: 1.7120x; 1.7120x over previous
//
#include <hip/hip_runtime.h>
#include <stdint.h>
#include <stddef.h>

// Reverse LSTM: T=256, B=64, D=H=1024.
// R16 = R14 (proven regular-launch persistent kernel) + two MALL-request cuts:
//   1) BLOCKED ring layout [wg][batch][16units]: publish = contiguous 2KB/WG
//      (was 64x 32B scatter); consumer h loads 256B-contiguous across lanes
//      (was 16 lines/instr + 2x overfetch). Register contents identical.
//   2) SINGLE epoch counter (atomicAdd 1/WG/step; poll one broadcast line,
//      was 64 distinct 128B lines per poll iteration).
// Everything else (roles, barriers, pipeline, macros, launch) R14 verbatim.

typedef unsigned short u16;
typedef __attribute__((ext_vector_type(4))) unsigned short u16x4;
typedef __attribute__((ext_vector_type(8))) short short8;
typedef __attribute__((ext_vector_type(4))) float f32x4;

#define T_LEN 256
#define YS_ELEMS (256 * 64 * 1024)  // 16777216

__device__ __forceinline__ u16 f2bf(float f) {
  union { float f; unsigned int i; } v; v.f = f;
  unsigned int r = v.i + 0x7FFFu + ((v.i >> 16) & 1u);  // RNE
  return (u16)(r >> 16);
}
__device__ __forceinline__ float bf2f(u16 u) {
  union { unsigned int i; float f; } v; v.i = ((unsigned int)u) << 16; return v.f;
}
__device__ __forceinline__ void gload_lds16(const void* g, void* l) {
  __builtin_amdgcn_global_load_lds(
      (const __attribute__((address_space(1))) unsigned int*)g,
      (__attribute__((address_space(3))) unsigned int*)l, 16, 0, 0);
}
__device__ __forceinline__ float sigm_fast(float x) { return 1.f / (1.f + __expf(-x)); }

// plain CACHED 16B load with compile-time byte offset (no wait; counted vmcnt)
#define ISSUE_LD16C(dst, ptr, off)                                      \
  asm volatile("global_load_dwordx4 %0, %1, off offset:%c2"             \
               : "=v"(dst) : "v"(ptr), "i"(off) : "memory")

// plain cached 8B load (vmcnt-ordered among our asm ops)
#define LD8_PLAIN(dst, ptr)                                             \
  asm volatile("global_load_dwordx2 %0, %1, off"                        \
               : "=v"(dst) : "v"(ptr) : "memory")

// device-coherent 8B write-through store (to MALL home)
#define ST8_WT(ptr, val)                                                \
  asm volatile("global_store_dwordx2 %0, %1, off sc0 sc1"               \
               :: "v"(ptr), "v"(val) : "memory")

#define WAIT_VM16() do { asm volatile("s_waitcnt vmcnt(16)" ::: "memory"); \
                         __builtin_amdgcn_sched_barrier(0); } while (0)
#define WAIT_VM0()  do { asm volatile("s_waitcnt vmcnt(0)"  ::: "memory"); \
                         __builtin_amdgcn_sched_barrier(0); } while (0)

// ---------------- Phase 0 ----------------
__global__ void cast_f32_bf16(const float* __restrict__ src, u16* __restrict__ dst, int n4) {
  int i = blockIdx.x * blockDim.x + threadIdx.x;
  const int stride = gridDim.x * blockDim.x;
  for (; i < n4; i += stride) {
    float4 v = ((const float4*)src)[i];
    u16x4 o;
    o[0] = f2bf(v.x); o[1] = f2bf(v.y); o[2] = f2bf(v.z); o[3] = f2bf(v.w);
    ((u16x4*)dst)[i] = o;
  }
}

// h0 [64][1024] f32 -> ring[0] in BLOCKED layout [blk=j/16][b][j%16] bf16
__global__ void scat_h0(const float* __restrict__ src, u16* __restrict__ dst) {
  int i = blockIdx.x * blockDim.x + threadIdx.x;   // 0..8191, 8 elems each
  const int b = i >> 7;
  const int j0 = (i & 127) * 8;
  const float4 v0 = ((const float4*)src)[i * 2];
  const float4 v1 = ((const float4*)src)[i * 2 + 1];
  short8 pk;
  pk[0] = (short)f2bf(v0.x); pk[1] = (short)f2bf(v0.y);
  pk[2] = (short)f2bf(v0.z); pk[3] = (short)f2bf(v0.w);
  pk[4] = (short)f2bf(v1.x); pk[5] = (short)f2bf(v1.y);
  pk[6] = (short)f2bf(v1.z); pk[7] = (short)f2bf(v1.w);
  *(short8*)(dst + (size_t)(j0 >> 4) * 1024 + b * 16 + (j0 & 15)) = pk;
}

// diagnostic canary: out[0] = 100 (lstm_rec overwrites it at si=255)
__global__ void canary_k(float* __restrict__ out) { out[0] = 100.0f; }

// ---------------- Phase 1: pregate GEMM (proven, unchanged) ----------------
__global__ __launch_bounds__(256, 2) void gemm_pre(
    const u16* __restrict__ X, const u16* __restrict__ Wih,
    const float* __restrict__ bih, const float* __restrict__ bhh,
    u16* __restrict__ Pout)
{
  __shared__ u16 As[128 * 64];
  __shared__ u16 Bs[128 * 64];
  const int tid = threadIdx.x;
  const int lane = tid & 63;
  const int wid = tid >> 6;
  const int wm = wid & 1, wn = wid >> 1;
  const int Mt = blockIdx.x, Nt = blockIdx.y;

  f32x4 acc[4][4] = {};
  const int rsub = lane >> 3;
  const int src_chunk = (lane & 7) ^ rsub;

  for (int it = 0; it < 16; ++it) {
    const int k0 = it * 64;
    #pragma unroll
    for (int q = 0; q < 4; ++q) {
      const int j = wid * 4 + q;
      const int row_local = j * 8 + rsub;
      const u16* ga = X   + ((size_t)(Mt * 128 + row_local)) * 1024 + k0 + src_chunk * 8;
      const u16* gb = Wih + ((size_t)(Nt * 128 + row_local)) * 1024 + k0 + src_chunk * 8;
      gload_lds16(ga, (char*)As + j * 1024);
      gload_lds16(gb, (char*)Bs + j * 1024);
    }
    __syncthreads();
    #pragma unroll
    for (int ks = 0; ks < 2; ++ks) {
      short8 af[4], bfv[4];
      #pragma unroll
      for (int f = 0; f < 4; ++f) {
        const int ra = wm * 64 + f * 16 + (lane & 15);
        const int rb = wn * 64 + f * 16 + (lane & 15);
        const int kc = ks * 4 + (lane >> 4);
        af[f]  = *(const short8*)((const char*)As + ra * 128 + ((kc ^ (ra & 7)) << 4));
        bfv[f] = *(const short8*)((const char*)Bs + rb * 128 + ((kc ^ (rb & 7)) << 4));
      }
      #pragma unroll
      for (int fm = 0; fm < 4; ++fm)
        #pragma unroll
        for (int fn = 0; fn < 4; ++fn)
          acc[fm][fn] = __builtin_amdgcn_mfma_f32_16x16x32_bf16(af[fm], bfv[fn], acc[fm][fn], 0, 0, 0);
    }
    __syncthreads();
  }

  const int t_out = Mt * 2 + wm;
  #pragma unroll
  for (int fn = 0; fn < 4; ++fn) {
    const int n = Nt * 128 + wn * 64 + fn * 16 + (lane & 15);
    const float bias = bih[n] + bhh[n];
    #pragma unroll
    for (int fm = 0; fm < 4; ++fm) {
      const int b = fm * 16 + ((lane >> 4) << 2);
      u16x4 o;
      #pragma unroll
      for (int r = 0; r < 4; ++r) o[r] = f2bf(acc[fm][fn][r] + bias);
      *(u16x4*)(Pout + ((size_t)t_out * 4096 + n) * 64 + b) = o;
    }
  }
}

// ---------------- Phase 2: persistent recurrence ----------------
// Static LDS = 131072 + 16384 = 147456 B. Regular launch, 64 WGs (co-resident).
__global__ __launch_bounds__(256, 1) void lstm_rec(
    const u16* __restrict__ P, const float* __restrict__ c0,
    const float* __restrict__ Whh, u16* __restrict__ ring,
    float* __restrict__ out, int* __restrict__ cnt)
{
  __shared__ u16 Ws[64 * 1024];
  __shared__ float GX[4096];     // gate exchange; first 2KB reused as HXu

  const int tid = threadIdx.x;
  const int lane = tid & 63;
  const int wid = tid >> 6;
  const int wg = blockIdx.x;

  // one-time W_hh slice -> LDS (bf16, XOR-swizzled rows)  [R14 verbatim]
  {
    const int rowp = tid >> 2;
    const int q = tid & 3;
    const int grow = (rowp >> 4) * 1024 + wg * 16 + (rowp & 15);
    const float4* src = (const float4*)(Whh + (size_t)grow * 1024 + q * 256);
    #pragma unroll 2
    for (int j = 0; j < 32; ++j) {
      float4 v0 = src[j * 2];
      float4 v1 = src[j * 2 + 1];
      short8 pk;
      pk[0] = (short)f2bf(v0.x); pk[1] = (short)f2bf(v0.y);
      pk[2] = (short)f2bf(v0.z); pk[3] = (short)f2bf(v0.w);
      pk[4] = (short)f2bf(v1.x); pk[5] = (short)f2bf(v1.y);
      pk[6] = (short)f2bf(v1.z); pk[7] = (short)f2bf(v1.w);
      const int kc = q * 32 + j;
      *(short8*)((char*)Ws + rowp * 2048 + ((kc ^ (rowp & 7)) << 4)) = pk;
    }
  }

  // pointwise role: unit u, batches b0..b0+3  [R14 verbatim]
  const int u = tid & 15;
  const int b0 = (tid >> 4) << 2;
  const int jh = wg * 16 + u;
  float cs[4];
  #pragma unroll
  for (int r = 0; r < 4; ++r) cs[r] = c0[(size_t)(b0 + r) * 1024 + jh];

  const int wm = wid & 1;
  const int wn = wid >> 1;
  const int kpos = lane >> 4;    // 0..3: k-subposition within a 32-unit K-slice

  u16* HXu = (u16*)GX;

  __syncthreads();

  // blocked-layout A-fragment base: blk=(kpos>>1), elem-off=(kpos&1)*8, row stride 16
  // ISSUE_Q(qi): j_abs = qi*256 + kq*32 + kpos*8 -> addr = blk*1024 + row*16 + off
  #define ISSUE_Q(buf, qi) {                                                   \
    const u16* bq_ = pA + (size_t)(qi) * 16384;                                \
    _Pragma("unroll")                                                          \
    for (int kq_ = 0; kq_ < 8; ++kq_) {                                        \
      const u16* pk_ = bq_ + kq_ * 2048;                                       \
      ISSUE_LD16C(buf[kq_][0], pk_, 0);     /* rows wm*32..+16 */              \
      ISSUE_LD16C(buf[kq_][1], pk_, 512);   /* rows +16 (16 rows x 16 units) */\
    } }

  #define MFMA_Q(buf, qi) {                                                    \
    _Pragma("unroll")                                                          \
    for (int kq_ = 0; kq_ < 8; ++kq_) {                                        \
      const int kabs_ = (qi) * 8 + kq_;                                        \
      _Pragma("unroll")                                                        \
      for (int ni_ = 0; ni_ < 2; ++ni_) {                                      \
        const int rs_ = wn * 32 + ni_ * 16 + (lane & 15);                      \
        const int kcl_ = kabs_ * 4 + (lane >> 4);                              \
        const short8 bfr_ = *(const short8*)((const char*)Ws + rs_ * 2048      \
                            + ((kcl_ ^ (rs_ & 7)) << 4));                      \
        acc[0][ni_] = __builtin_amdgcn_mfma_f32_16x16x32_bf16(buf[kq_][0], bfr_, acc[0][ni_], 0, 0, 0); \
        acc[1][ni_] = __builtin_amdgcn_mfma_f32_16x16x32_bf16(buf[kq_][1], bfr_, acc[1][ni_], 0, 0, 0); \
      } } }

  for (int si = 0; si < 256; ++si) {
    const int t = 255 - si;
    const u16* rb = ring + (size_t)si * 65536;

    // blocked-layout per-lane base (register contents identical to R14's loads)
    const u16* pA = rb + (size_t)(kpos >> 1) * 1024 + (kpos & 1) * 8
                    + (wm * 32 + (lane & 15)) * 16;

    // P loads (asm 8B, oldest in vmcnt order)  [R14 verbatim]
    const size_t pbase = (size_t)t * 262144;
    unsigned long long Pi, Pf, Pg, Po;
    LD8_PLAIN(Pi, P + pbase + (size_t)(0 * 1024 + jh) * 64 + b0);
    LD8_PLAIN(Pf, P + pbase + (size_t)(1 * 1024 + jh) * 64 + b0);
    LD8_PLAIN(Pg, P + pbase + (size_t)(2 * 1024 + jh) * 64 + b0);
    LD8_PLAIN(Po, P + pbase + (size_t)(3 * 1024 + jh) * 64 + b0);

    f32x4 acc[2][2] = {};
    short8 afrA[8][2], afrB[8][2];

    // counted-vmcnt quarter pipeline  [R14 verbatim]
    ISSUE_Q(afrA, 0)
    ISSUE_Q(afrB, 1)
    WAIT_VM16(); MFMA_Q(afrA, 0)
    ISSUE_Q(afrA, 2)
    WAIT_VM16(); MFMA_Q(afrB, 1)
    ISSUE_Q(afrB, 3)
    WAIT_VM16(); MFMA_Q(afrA, 2)
    WAIT_VM0();  MFMA_Q(afrB, 3)

    // gate exchange through LDS  [R14 verbatim]
    #pragma unroll
    for (int mi = 0; mi < 2; ++mi)
      #pragma unroll
      for (int ni = 0; ni < 2; ++ni) {
        const int g = wn * 2 + ni;
        const int uu = lane & 15;
        const int bb = wm * 32 + mi * 16 + ((lane >> 4) << 2);
        *(f32x4*)((char*)GX + ((((g * 16 + uu) * 64 + bb) << 2) ^ ((uu & 7) << 4))) = acc[mi][ni];
      }
    __syncthreads();

    const f32x4 vi = *(const f32x4*)((char*)GX + ((((0 * 16 + u) * 64 + b0) << 2) ^ ((u & 7) << 4)));
    const f32x4 vf = *(const f32x4*)((char*)GX + ((((1 * 16 + u) * 64 + b0) << 2) ^ ((u & 7) << 4)));
    const f32x4 vg = *(const f32x4*)((char*)GX + ((((2 * 16 + u) * 64 + b0) << 2) ^ ((u & 7) << 4)));
    const f32x4 vo = *(const f32x4*)((char*)GX + ((((3 * 16 + u) * 64 + b0) << 2) ^ ((u & 7) << 4)));

    float hvv[4], cnn[4];
    #pragma unroll
    for (int r = 0; r < 4; ++r) {
      const float xi = vi[r] + bf2f((u16)(Pi >> (16 * r)));
      const float xf = vf[r] + bf2f((u16)(Pf >> (16 * r)));
      const float xg = vg[r] + bf2f((u16)(Pg >> (16 * r)));
      const float xo = vo[r] + bf2f((u16)(Po >> (16 * r)));
      const float ig = sigm_fast(xi);
      const float fg = sigm_fast(xf);
      const float og = sigm_fast(xo);
      const float cn = fg * cs[r] + ig * tanhf(xg);
      const float hv = og * tanhf(cn);
      cs[r] = cn; cnn[r] = cn; hvv[r] = hv;
    }

    if (si < 255) {
      __syncthreads();  // all GX gate reads done; safe to overwrite with HXu
      #pragma unroll
      for (int r = 0; r < 4; ++r) HXu[(b0 + r) * 16 + u] = f2bf(hvv[r]);
      __syncthreads();  // HXu complete
      // BLOCKED publish: HXu is already [b][16u] = the WG's 2KB ring block.
      // One contiguous 8B write-through store per thread (fully coalesced).
      {
        u16* wb = ring + (size_t)(si + 1) * 65536 + (size_t)wg * 1024;
        const unsigned long long hv8 = *(const unsigned long long*)(HXu + tid * 4);
        ST8_WT(wb + tid * 4, hv8);
      }
      WAIT_VM0();        // drain covers ONLY the 2KB publish (ys not yet issued)
      __syncthreads();   // whole WG drained
      if (tid == 0) atomicAdd(cnt, 1);   // single epoch counter
      // ys stores AFTER the flag — acks retire under the poll
      #pragma unroll
      for (int r = 0; r < 4; ++r)
        out[((size_t)t * 64 + b0 + r) * 1024 + jh] = hvv[r];
      if (tid < 64) {
        // one broadcast line: converged lanes -> a single MALL request per iter
        while (__hip_atomic_load(cnt, __ATOMIC_RELAXED, __HIP_MEMORY_SCOPE_AGENT)
               < (si + 1) * 64)
          __builtin_amdgcn_s_sleep(2);
      }
      __syncthreads();
    } else {
      #pragma unroll
      for (int r = 0; r < 4; ++r) {
        out[((size_t)t * 64 + b0 + r) * 1024 + jh] = hvv[r];            // ys t=0
        out[YS_ELEMS + (size_t)(b0 + r) * 1024 + jh] = hvv[r];          // hT
        out[YS_ELEMS + 65536 + (size_t)(b0 + r) * 1024 + jh] = cnn[r];  // cT
      }
    }
  }
  #undef ISSUE_Q
  #undef MFMA_Q
}

// ---------------- launch ----------------
extern "C" void kernel_launch(void* const* d_in, const int* in_sizes, int n_in,
                              void* d_out, int out_size, void* d_ws, size_t ws_size,
                              hipStream_t stream) {
  const float* x   = (const float*)d_in[0];
  const float* h0  = (const float*)d_in[1];
  const float* c0  = (const float*)d_in[2];
  const float* Wih = (const float*)d_in[3];
  const float* Whh = (const float*)d_in[4];
  const float* bih = (const float*)d_in[5];
  const float* bhh = (const float*)d_in[6];
  float* out = (float*)d_out;

  char* ws = (char*)d_ws;
  u16* x_bf   = (u16*)(ws + 0);           // 32MB; recycled as h ring after gemm_pre
  u16* ring   = (u16*)(ws + 0);           // 256 x 131072 B (blocked layout)
  u16* wih_bf = (u16*)(ws + 33554432);
  u16* Pp     = (u16*)(ws + 41943040);    // 128MB
  int* cnt    = (int*)(ws + 176160768);   // 128 B (single epoch counter line)

  hipLaunchKernelGGL(cast_f32_bf16, dim3(2048), dim3(256), 0, stream, x,   x_bf,   4194304);
  hipLaunchKernelGGL(cast_f32_bf16, dim3(1024), dim3(256), 0, stream, Wih, wih_bf, 1048576);
  hipLaunchKernelGGL(gemm_pre, dim3(128, 32), dim3(256), 0, stream, x_bf, wih_bf, bih, bhh, Pp);
  hipMemsetAsync(cnt, 0, 128, stream);
  hipLaunchKernelGGL(scat_h0, dim3(32), dim3(256), 0, stream, h0, ring);
  hipLaunchKernelGGL(canary_k, dim3(1), dim3(1), 0, stream, out);

  // REGULAR launch (not cooperative): 64 WGs, 1/CU -> trivially co-resident.
  hipLaunchKernelGGL(lstm_rec, dim3(64), dim3(256), 0, stream,
                     (const u16*)Pp, c0, Whh, ring, out, cnt);
}

// Round 17
// 1786.405 us; speedup vs baseline: 1.7369x; 1.0145x over previous
//
#include <hip/hip_runtime.h>
#include <stdint.h>
#include <stddef.h>

// Reverse LSTM: T=256, B=64, D=H=1024.
// R17 = R16 (blocked ring, proven) + seq-word release replacing the atomic:
//   - producer: blocked 2KB publish -> wave drain -> WG barrier -> tid0 writes
//     seqbuf[wg] = si+1 (4B sc0 sc1, fire-and-forget; ordered behind acked data)
//   - consumer: R15-proven per-quarter SPIN/CHK machinery gates quarter q on
//     its 16 producer seq words (16 distinct lines read in parallel; no RMW,
//     no same-line serialization), threaded into the counted-vmcnt pipeline.
//   - 3 barriers/step (was 4); ys stores fire-and-forget after the seq word.

typedef unsigned short u16;
typedef __attribute__((ext_vector_type(4))) unsigned short u16x4;
typedef __attribute__((ext_vector_type(8))) short short8;
typedef __attribute__((ext_vector_type(4))) float f32x4;

#define T_LEN 256
#define YS_ELEMS (256 * 64 * 1024)  // 16777216

__device__ __forceinline__ u16 f2bf(float f) {
  union { float f; unsigned int i; } v; v.f = f;
  unsigned int r = v.i + 0x7FFFu + ((v.i >> 16) & 1u);  // RNE
  return (u16)(r >> 16);
}
__device__ __forceinline__ float bf2f(u16 u) {
  union { unsigned int i; float f; } v; v.i = ((unsigned int)u) << 16; return v.f;
}
__device__ __forceinline__ void gload_lds16(const void* g, void* l) {
  __builtin_amdgcn_global_load_lds(
      (const __attribute__((address_space(1))) unsigned int*)g,
      (__attribute__((address_space(3))) unsigned int*)l, 16, 0, 0);
}
__device__ __forceinline__ float sigm_fast(float x) { return 1.f / (1.f + __expf(-x)); }

// plain CACHED 16B load with compile-time byte offset (no wait; counted vmcnt)
#define ISSUE_LD16C(dst, ptr, off)                                      \
  asm volatile("global_load_dwordx4 %0, %1, off offset:%c2"             \
               : "=v"(dst) : "v"(ptr), "i"(off) : "memory")

// plain cached 8B load (vmcnt-ordered among our asm ops)
#define LD8_PLAIN(dst, ptr)                                             \
  asm volatile("global_load_dwordx2 %0, %1, off"                        \
               : "=v"(dst) : "v"(ptr) : "memory")

// device-coherent 8B write-through store (to MALL home)
#define ST8_WT(ptr, val)                                                \
  asm volatile("global_store_dwordx2 %0, %1, off sc0 sc1"               \
               :: "v"(ptr), "v"(val) : "memory")

// device-coherent 4B write-through store (seq word)
#define ST4_WT(ptr, val)                                                \
  asm volatile("global_store_dword %0, %1, off sc0 sc1"                 \
               :: "v"(ptr), "v"(val) : "memory")

// device-coherent 4B seq-word load (counted; no implicit wait)
#define CHK_ISSUE(dst, qi)                                              \
  asm volatile("global_load_dword %0, %1, off sc0 sc1"                  \
               : "=v"(dst) : "v"(seqb + ((((qi) * 16 + flid)) << 5)) : "memory")

#define WAIT_VMN(n) do { asm volatile("s_waitcnt vmcnt(" #n ")" ::: "memory"); \
                         __builtin_amdgcn_sched_barrier(0); } while (0)

// spin: fast path = register test only; slow path re-issues the seq load
#define SPIN_Q(fq, qi) do {                                              \
    while (!__all(fq >= lim)) {                                          \
      __builtin_amdgcn_s_sleep(1);                                       \
      CHK_ISSUE(fq, qi);                                                 \
      WAIT_VMN(0);                                                       \
    }                                                                    \
  } while (0)

// ---------------- Phase 0 ----------------
__global__ void cast_f32_bf16(const float* __restrict__ src, u16* __restrict__ dst, int n4) {
  int i = blockIdx.x * blockDim.x + threadIdx.x;
  const int stride = gridDim.x * blockDim.x;
  for (; i < n4; i += stride) {
    float4 v = ((const float4*)src)[i];
    u16x4 o;
    o[0] = f2bf(v.x); o[1] = f2bf(v.y); o[2] = f2bf(v.z); o[3] = f2bf(v.w);
    ((u16x4*)dst)[i] = o;
  }
}

// h0 [64][1024] f32 -> ring[0] in BLOCKED layout [blk=j/16][b][j%16] bf16
__global__ void scat_h0(const float* __restrict__ src, u16* __restrict__ dst) {
  int i = blockIdx.x * blockDim.x + threadIdx.x;   // 0..8191, 8 elems each
  const int b = i >> 7;
  const int j0 = (i & 127) * 8;
  const float4 v0 = ((const float4*)src)[i * 2];
  const float4 v1 = ((const float4*)src)[i * 2 + 1];
  short8 pk;
  pk[0] = (short)f2bf(v0.x); pk[1] = (short)f2bf(v0.y);
  pk[2] = (short)f2bf(v0.z); pk[3] = (short)f2bf(v0.w);
  pk[4] = (short)f2bf(v1.x); pk[5] = (short)f2bf(v1.y);
  pk[6] = (short)f2bf(v1.z); pk[7] = (short)f2bf(v1.w);
  *(short8*)(dst + (size_t)(j0 >> 4) * 1024 + b * 16 + (j0 & 15)) = pk;
}

// diagnostic canary: out[0] = 100 (lstm_rec overwrites it at si=255)
__global__ void canary_k(float* __restrict__ out) { out[0] = 100.0f; }

// ---------------- Phase 1: pregate GEMM (proven, unchanged) ----------------
__global__ __launch_bounds__(256, 2) void gemm_pre(
    const u16* __restrict__ X, const u16* __restrict__ Wih,
    const float* __restrict__ bih, const float* __restrict__ bhh,
    u16* __restrict__ Pout)
{
  __shared__ u16 As[128 * 64];
  __shared__ u16 Bs[128 * 64];
  const int tid = threadIdx.x;
  const int lane = tid & 63;
  const int wid = tid >> 6;
  const int wm = wid & 1, wn = wid >> 1;
  const int Mt = blockIdx.x, Nt = blockIdx.y;

  f32x4 acc[4][4] = {};
  const int rsub = lane >> 3;
  const int src_chunk = (lane & 7) ^ rsub;

  for (int it = 0; it < 16; ++it) {
    const int k0 = it * 64;
    #pragma unroll
    for (int q = 0; q < 4; ++q) {
      const int j = wid * 4 + q;
      const int row_local = j * 8 + rsub;
      const u16* ga = X   + ((size_t)(Mt * 128 + row_local)) * 1024 + k0 + src_chunk * 8;
      const u16* gb = Wih + ((size_t)(Nt * 128 + row_local)) * 1024 + k0 + src_chunk * 8;
      gload_lds16(ga, (char*)As + j * 1024);
      gload_lds16(gb, (char*)Bs + j * 1024);
    }
    __syncthreads();
    #pragma unroll
    for (int ks = 0; ks < 2; ++ks) {
      short8 af[4], bfv[4];
      #pragma unroll
      for (int f = 0; f < 4; ++f) {
        const int ra = wm * 64 + f * 16 + (lane & 15);
        const int rb = wn * 64 + f * 16 + (lane & 15);
        const int kc = ks * 4 + (lane >> 4);
        af[f]  = *(const short8*)((const char*)As + ra * 128 + ((kc ^ (ra & 7)) << 4));
        bfv[f] = *(const short8*)((const char*)Bs + rb * 128 + ((kc ^ (rb & 7)) << 4));
      }
      #pragma unroll
      for (int fm = 0; fm < 4; ++fm)
        #pragma unroll
        for (int fn = 0; fn < 4; ++fn)
          acc[fm][fn] = __builtin_amdgcn_mfma_f32_16x16x32_bf16(af[fm], bfv[fn], acc[fm][fn], 0, 0, 0);
    }
    __syncthreads();
  }

  const int t_out = Mt * 2 + wm;
  #pragma unroll
  for (int fn = 0; fn < 4; ++fn) {
    const int n = Nt * 128 + wn * 64 + fn * 16 + (lane & 15);
    const float bias = bih[n] + bhh[n];
    #pragma unroll
    for (int fm = 0; fm < 4; ++fm) {
      const int b = fm * 16 + ((lane >> 4) << 2);
      u16x4 o;
      #pragma unroll
      for (int r = 0; r < 4; ++r) o[r] = f2bf(acc[fm][fn][r] + bias);
      *(u16x4*)(Pout + ((size_t)t_out * 4096 + n) * 64 + b) = o;
    }
  }
}

// ---------------- Phase 2: persistent recurrence ----------------
// Static LDS = 131072 + 16384 = 147456 B. Regular launch, 64 WGs (co-resident).
__global__ __launch_bounds__(256, 1) void lstm_rec(
    const u16* __restrict__ P, const float* __restrict__ c0,
    const float* __restrict__ Whh, u16* __restrict__ ring,
    float* __restrict__ out, int* __restrict__ seqb)
{
  __shared__ u16 Ws[64 * 1024];
  __shared__ float GX[4096];     // gate exchange; first 2KB reused as HXu

  const int tid = threadIdx.x;
  const int lane = tid & 63;
  const int wid = tid >> 6;
  const int wg = blockIdx.x;

  // one-time W_hh slice -> LDS (bf16, XOR-swizzled rows)  [R16 verbatim]
  {
    const int rowp = tid >> 2;
    const int q = tid & 3;
    const int grow = (rowp >> 4) * 1024 + wg * 16 + (rowp & 15);
    const float4* src = (const float4*)(Whh + (size_t)grow * 1024 + q * 256);
    #pragma unroll 2
    for (int j = 0; j < 32; ++j) {
      float4 v0 = src[j * 2];
      float4 v1 = src[j * 2 + 1];
      short8 pk;
      pk[0] = (short)f2bf(v0.x); pk[1] = (short)f2bf(v0.y);
      pk[2] = (short)f2bf(v0.z); pk[3] = (short)f2bf(v0.w);
      pk[4] = (short)f2bf(v1.x); pk[5] = (short)f2bf(v1.y);
      pk[6] = (short)f2bf(v1.z); pk[7] = (short)f2bf(v1.w);
      const int kc = q * 32 + j;
      *(short8*)((char*)Ws + rowp * 2048 + ((kc ^ (rowp & 7)) << 4)) = pk;
    }
  }

  // pointwise role: unit u, batches b0..b0+3  [R16 verbatim]
  const int u = tid & 15;
  const int b0 = (tid >> 4) << 2;
  const int jh = wg * 16 + u;
  float cs[4];
  #pragma unroll
  for (int r = 0; r < 4; ++r) cs[r] = c0[(size_t)(b0 + r) * 1024 + jh];

  const int wm = wid & 1;
  const int wn = wid >> 1;
  const int kpos = lane >> 4;    // 0..3: k-subposition within a 32-unit K-slice
  const int flid = lane & 15;    // seq-word lane id

  u16* HXu = (u16*)GX;

  __syncthreads();

  // blocked-layout A-fragment loads  [R16 verbatim]
  #define ISSUE_Q(buf, qi) {                                                   \
    const u16* bq_ = pA + (size_t)(qi) * 16384;                                \
    _Pragma("unroll")                                                          \
    for (int kq_ = 0; kq_ < 8; ++kq_) {                                        \
      const u16* pk_ = bq_ + kq_ * 2048;                                       \
      ISSUE_LD16C(buf[kq_][0], pk_, 0);                                        \
      ISSUE_LD16C(buf[kq_][1], pk_, 512);                                      \
    } }

  #define MFMA_Q(buf, qi) {                                                    \
    _Pragma("unroll")                                                          \
    for (int kq_ = 0; kq_ < 8; ++kq_) {                                        \
      const int kabs_ = (qi) * 8 + kq_;                                        \
      _Pragma("unroll")                                                        \
      for (int ni_ = 0; ni_ < 2; ++ni_) {                                      \
        const int rs_ = wn * 32 + ni_ * 16 + (lane & 15);                      \
        const int kcl_ = kabs_ * 4 + (lane >> 4);                              \
        const short8 bfr_ = *(const short8*)((const char*)Ws + rs_ * 2048      \
                            + ((kcl_ ^ (rs_ & 7)) << 4));                      \
        acc[0][ni_] = __builtin_amdgcn_mfma_f32_16x16x32_bf16(buf[kq_][0], bfr_, acc[0][ni_], 0, 0, 0); \
        acc[1][ni_] = __builtin_amdgcn_mfma_f32_16x16x32_bf16(buf[kq_][1], bfr_, acc[1][ni_], 0, 0, 0); \
      } } }

  for (int si = 0; si < 256; ++si) {
    const int t = 255 - si;
    const int lim = si;             // seq value required for this step's h
    const u16* rb = ring + (size_t)si * 65536;

    // blocked-layout per-lane base  [R16 verbatim]
    const u16* pA = rb + (size_t)(kpos >> 1) * 1024 + (kpos & 1) * 8
                    + (wm * 32 + (lane & 15)) * 16;

    // seq snapshot (oldest), then P loads (newest-4)
    int f0, f1, f2, f3;
    CHK_ISSUE(f0, 0); CHK_ISSUE(f1, 1); CHK_ISSUE(f2, 2); CHK_ISSUE(f3, 3);
    const size_t pbase = (size_t)t * 262144;
    unsigned long long Pi, Pf, Pg, Po;
    LD8_PLAIN(Pi, P + pbase + (size_t)(0 * 1024 + jh) * 64 + b0);
    LD8_PLAIN(Pf, P + pbase + (size_t)(1 * 1024 + jh) * 64 + b0);
    LD8_PLAIN(Pg, P + pbase + (size_t)(2 * 1024 + jh) * 64 + b0);
    LD8_PLAIN(Po, P + pbase + (size_t)(3 * 1024 + jh) * 64 + b0);
    WAIT_VMN(4);          // seq snapshot valid (P may be outstanding)

    f32x4 acc[2][2] = {};
    short8 afrA[8][2], afrB[8][2];

    // per-quarter gated counted pipeline (waits are younger-count invariant)
    SPIN_Q(f0, 0);
    ISSUE_Q(afrA, 0)
    SPIN_Q(f1, 1);
    ISSUE_Q(afrB, 1)
    WAIT_VMN(16); MFMA_Q(afrA, 0)    // P + q0 retired (q1 = newest 16)
    SPIN_Q(f2, 2);
    ISSUE_Q(afrA, 2)
    WAIT_VMN(16); MFMA_Q(afrB, 1)
    SPIN_Q(f3, 3);
    ISSUE_Q(afrB, 3)
    WAIT_VMN(16); MFMA_Q(afrA, 2)
    WAIT_VMN(0);  MFMA_Q(afrB, 3)

    // gate exchange through LDS  [R16 verbatim]
    #pragma unroll
    for (int mi = 0; mi < 2; ++mi)
      #pragma unroll
      for (int ni = 0; ni < 2; ++ni) {
        const int g = wn * 2 + ni;
        const int uu = lane & 15;
        const int bb = wm * 32 + mi * 16 + ((lane >> 4) << 2);
        *(f32x4*)((char*)GX + ((((g * 16 + uu) * 64 + bb) << 2) ^ ((uu & 7) << 4))) = acc[mi][ni];
      }
    __syncthreads();

    const f32x4 vi = *(const f32x4*)((char*)GX + ((((0 * 16 + u) * 64 + b0) << 2) ^ ((u & 7) << 4)));
    const f32x4 vf = *(const f32x4*)((char*)GX + ((((1 * 16 + u) * 64 + b0) << 2) ^ ((u & 7) << 4)));
    const f32x4 vg = *(const f32x4*)((char*)GX + ((((2 * 16 + u) * 64 + b0) << 2) ^ ((u & 7) << 4)));
    const f32x4 vo = *(const f32x4*)((char*)GX + ((((3 * 16 + u) * 64 + b0) << 2) ^ ((u & 7) << 4)));

    float hvv[4], cnn[4];
    #pragma unroll
    for (int r = 0; r < 4; ++r) {
      const float xi = vi[r] + bf2f((u16)(Pi >> (16 * r)));
      const float xf = vf[r] + bf2f((u16)(Pf >> (16 * r)));
      const float xg = vg[r] + bf2f((u16)(Pg >> (16 * r)));
      const float xo = vo[r] + bf2f((u16)(Po >> (16 * r)));
      const float ig = sigm_fast(xi);
      const float fg = sigm_fast(xf);
      const float og = sigm_fast(xo);
      const float cn = fg * cs[r] + ig * tanhf(xg);
      const float hv = og * tanhf(cn);
      cs[r] = cn; cnn[r] = cn; hvv[r] = hv;
    }

    if (si < 255) {
      __syncthreads();  // all GX gate reads done; safe to overwrite with HXu
      #pragma unroll
      for (int r = 0; r < 4; ++r) HXu[(b0 + r) * 16 + u] = f2bf(hvv[r]);
      __syncthreads();  // HXu complete
      // BLOCKED publish: one contiguous 8B write-through store per thread
      {
        u16* wb = ring + (size_t)(si + 1) * 65536 + (size_t)wg * 1024;
        const unsigned long long hv8 = *(const unsigned long long*)(HXu + tid * 4);
        ST8_WT(wb + tid * 4, hv8);
      }
      WAIT_VMN(0);       // this wave's publish performed at MALL
      __syncthreads();   // whole WG drained
      // release: one 4B seq word per WG (no RMW, no same-line contention)
      if (tid == 0) ST4_WT(seqb + (wg << 5), si + 1);
      // ys stores fire-and-forget (acks retire under next step's waits)
      #pragma unroll
      for (int r = 0; r < 4; ++r)
        out[((size_t)t * 64 + b0 + r) * 1024 + jh] = hvv[r];
      // no trailing barrier: next-step spins are per-wave; GX reuse is safe
      // (all GX reads of this step happened before the HXu barrier above)
    } else {
      #pragma unroll
      for (int r = 0; r < 4; ++r) {
        out[((size_t)t * 64 + b0 + r) * 1024 + jh] = hvv[r];            // ys t=0
        out[YS_ELEMS + (size_t)(b0 + r) * 1024 + jh] = hvv[r];          // hT
        out[YS_ELEMS + 65536 + (size_t)(b0 + r) * 1024 + jh] = cnn[r];  // cT
      }
    }
  }
  #undef ISSUE_Q
  #undef MFMA_Q
}

// ---------------- launch ----------------
extern "C" void kernel_launch(void* const* d_in, const int* in_sizes, int n_in,
                              void* d_out, int out_size, void* d_ws, size_t ws_size,
                              hipStream_t stream) {
  const float* x   = (const float*)d_in[0];
  const float* h0  = (const float*)d_in[1];
  const float* c0  = (const float*)d_in[2];
  const float* Wih = (const float*)d_in[3];
  const float* Whh = (const float*)d_in[4];
  const float* bih = (const float*)d_in[5];
  const float* bhh = (const float*)d_in[6];
  float* out = (float*)d_out;

  char* ws = (char*)d_ws;
  u16* x_bf   = (u16*)(ws + 0);           // 32MB; recycled as h ring after gemm_pre
  u16* ring   = (u16*)(ws + 0);           // 256 x 131072 B (blocked layout)
  u16* wih_bf = (u16*)(ws + 33554432);
  u16* Pp     = (u16*)(ws + 41943040);    // 128MB
  int* seqb   = (int*)(ws + 176160768);   // 8KB (64 seq words, 128B-padded)

  hipLaunchKernelGGL(cast_f32_bf16, dim3(2048), dim3(256), 0, stream, x,   x_bf,   4194304);
  hipLaunchKernelGGL(cast_f32_bf16, dim3(1024), dim3(256), 0, stream, Wih, wih_bf, 1048576);
  hipLaunchKernelGGL(gemm_pre, dim3(128, 32), dim3(256), 0, stream, x_bf, wih_bf, bih, bhh, Pp);
  hipMemsetAsync(seqb, 0, 8192, stream);
  hipLaunchKernelGGL(scat_h0, dim3(32), dim3(256), 0, stream, h0, ring);
  hipLaunchKernelGGL(canary_k, dim3(1), dim3(1), 0, stream, out);

  // REGULAR launch (not cooperative): 64 WGs, 1/CU -> trivially co-resident.
  hipLaunchKernelGGL(lstm_rec, dim3(64), dim3(256), 0, stream,
                     (const u16*)Pp, c0, Whh, ring, out, seqb);
}

// Round 18
// 1781.275 us; speedup vs baseline: 1.7419x; 1.0029x over previous
//
#include <hip/hip_runtime.h>
#include <stdint.h>
#include <stddef.h>

// Reverse LSTM: T=256, B=64, D=H=1024.
// R18 = R17 (proven) + three latency micro-cuts:
//   1) bf16 gate exchange GXb (8KB) + SEPARATE HXs staging (2KB): h-staging
//      exchange is intra-wave (lgkmcnt only) -> 2 barriers/step instead of 4.
//      LDS = 128K + 8K + 2K = 141312 B (< proven 147456 limit).
//   2) no-sleep 2-phase spin (poll at MALL RT rate, no 64cy sleep quantum).
//   3) gates pass through bf16 (precision margin 3.4x, predicted absmax <=0.016).

typedef unsigned short u16;
typedef __attribute__((ext_vector_type(4))) unsigned short u16x4;
typedef __attribute__((ext_vector_type(8))) short short8;
typedef __attribute__((ext_vector_type(4))) float f32x4;

#define T_LEN 256
#define YS_ELEMS (256 * 64 * 1024)  // 16777216

__device__ __forceinline__ u16 f2bf(float f) {
  union { float f; unsigned int i; } v; v.f = f;
  unsigned int r = v.i + 0x7FFFu + ((v.i >> 16) & 1u);  // RNE
  return (u16)(r >> 16);
}
__device__ __forceinline__ float bf2f(u16 u) {
  union { unsigned int i; float f; } v; v.i = ((unsigned int)u) << 16; return v.f;
}
__device__ __forceinline__ void gload_lds16(const void* g, void* l) {
  __builtin_amdgcn_global_load_lds(
      (const __attribute__((address_space(1))) unsigned int*)g,
      (__attribute__((address_space(3))) unsigned int*)l, 16, 0, 0);
}
__device__ __forceinline__ float sigm_fast(float x) { return 1.f / (1.f + __expf(-x)); }

// plain CACHED 16B load with compile-time byte offset (no wait; counted vmcnt)
#define ISSUE_LD16C(dst, ptr, off)                                      \
  asm volatile("global_load_dwordx4 %0, %1, off offset:%c2"             \
               : "=v"(dst) : "v"(ptr), "i"(off) : "memory")

// plain cached 8B load (vmcnt-ordered among our asm ops)
#define LD8_PLAIN(dst, ptr)                                             \
  asm volatile("global_load_dwordx2 %0, %1, off"                        \
               : "=v"(dst) : "v"(ptr) : "memory")

// device-coherent 8B write-through store (to MALL home)
#define ST8_WT(ptr, val)                                                \
  asm volatile("global_store_dwordx2 %0, %1, off sc0 sc1"               \
               :: "v"(ptr), "v"(val) : "memory")

// device-coherent 4B write-through store (seq word)
#define ST4_WT(ptr, val)                                                \
  asm volatile("global_store_dword %0, %1, off sc0 sc1"                 \
               :: "v"(ptr), "v"(val) : "memory")

// device-coherent 4B seq-word load (counted; no implicit wait)
#define CHK_ISSUE(dst, qi)                                              \
  asm volatile("global_load_dword %0, %1, off sc0 sc1"                  \
               : "=v"(dst) : "v"(seqb + ((((qi) * 16 + flid)) << 5)) : "memory")

#define WAIT_VMN(n) do { asm volatile("s_waitcnt vmcnt(" #n ")" ::: "memory"); \
                         __builtin_amdgcn_sched_barrier(0); } while (0)

// no-sleep spin: poll at MALL round-trip rate
#define SPIN_Q(fq, qi) do {                                              \
    while (!__all(fq >= lim)) {                                          \
      CHK_ISSUE(fq, qi);                                                 \
      WAIT_VMN(0);                                                       \
    }                                                                    \
  } while (0)

// ---------------- Phase 0 ----------------
__global__ void cast_f32_bf16(const float* __restrict__ src, u16* __restrict__ dst, int n4) {
  int i = blockIdx.x * blockDim.x + threadIdx.x;
  const int stride = gridDim.x * blockDim.x;
  for (; i < n4; i += stride) {
    float4 v = ((const float4*)src)[i];
    u16x4 o;
    o[0] = f2bf(v.x); o[1] = f2bf(v.y); o[2] = f2bf(v.z); o[3] = f2bf(v.w);
    ((u16x4*)dst)[i] = o;
  }
}

// h0 [64][1024] f32 -> ring[0] in BLOCKED layout [blk=j/16][b][j%16] bf16
__global__ void scat_h0(const float* __restrict__ src, u16* __restrict__ dst) {
  int i = blockIdx.x * blockDim.x + threadIdx.x;   // 0..8191, 8 elems each
  const int b = i >> 7;
  const int j0 = (i & 127) * 8;
  const float4 v0 = ((const float4*)src)[i * 2];
  const float4 v1 = ((const float4*)src)[i * 2 + 1];
  short8 pk;
  pk[0] = (short)f2bf(v0.x); pk[1] = (short)f2bf(v0.y);
  pk[2] = (short)f2bf(v0.z); pk[3] = (short)f2bf(v0.w);
  pk[4] = (short)f2bf(v1.x); pk[5] = (short)f2bf(v1.y);
  pk[6] = (short)f2bf(v1.z); pk[7] = (short)f2bf(v1.w);
  *(short8*)(dst + (size_t)(j0 >> 4) * 1024 + b * 16 + (j0 & 15)) = pk;
}

// diagnostic canary: out[0] = 100 (lstm_rec overwrites it at si=255)
__global__ void canary_k(float* __restrict__ out) { out[0] = 100.0f; }

// ---------------- Phase 1: pregate GEMM (proven, unchanged) ----------------
__global__ __launch_bounds__(256, 2) void gemm_pre(
    const u16* __restrict__ X, const u16* __restrict__ Wih,
    const float* __restrict__ bih, const float* __restrict__ bhh,
    u16* __restrict__ Pout)
{
  __shared__ u16 As[128 * 64];
  __shared__ u16 Bs[128 * 64];
  const int tid = threadIdx.x;
  const int lane = tid & 63;
  const int wid = tid >> 6;
  const int wm = wid & 1, wn = wid >> 1;
  const int Mt = blockIdx.x, Nt = blockIdx.y;

  f32x4 acc[4][4] = {};
  const int rsub = lane >> 3;
  const int src_chunk = (lane & 7) ^ rsub;

  for (int it = 0; it < 16; ++it) {
    const int k0 = it * 64;
    #pragma unroll
    for (int q = 0; q < 4; ++q) {
      const int j = wid * 4 + q;
      const int row_local = j * 8 + rsub;
      const u16* ga = X   + ((size_t)(Mt * 128 + row_local)) * 1024 + k0 + src_chunk * 8;
      const u16* gb = Wih + ((size_t)(Nt * 128 + row_local)) * 1024 + k0 + src_chunk * 8;
      gload_lds16(ga, (char*)As + j * 1024);
      gload_lds16(gb, (char*)Bs + j * 1024);
    }
    __syncthreads();
    #pragma unroll
    for (int ks = 0; ks < 2; ++ks) {
      short8 af[4], bfv[4];
      #pragma unroll
      for (int f = 0; f < 4; ++f) {
        const int ra = wm * 64 + f * 16 + (lane & 15);
        const int rb = wn * 64 + f * 16 + (lane & 15);
        const int kc = ks * 4 + (lane >> 4);
        af[f]  = *(const short8*)((const char*)As + ra * 128 + ((kc ^ (ra & 7)) << 4));
        bfv[f] = *(const short8*)((const char*)Bs + rb * 128 + ((kc ^ (rb & 7)) << 4));
      }
      #pragma unroll
      for (int fm = 0; fm < 4; ++fm)
        #pragma unroll
        for (int fn = 0; fn < 4; ++fn)
          acc[fm][fn] = __builtin_amdgcn_mfma_f32_16x16x32_bf16(af[fm], bfv[fn], acc[fm][fn], 0, 0, 0);
    }
    __syncthreads();
  }

  const int t_out = Mt * 2 + wm;
  #pragma unroll
  for (int fn = 0; fn < 4; ++fn) {
    const int n = Nt * 128 + wn * 64 + fn * 16 + (lane & 15);
    const float bias = bih[n] + bhh[n];
    #pragma unroll
    for (int fm = 0; fm < 4; ++fm) {
      const int b = fm * 16 + ((lane >> 4) << 2);
      u16x4 o;
      #pragma unroll
      for (int r = 0; r < 4; ++r) o[r] = f2bf(acc[fm][fn][r] + bias);
      *(u16x4*)(Pout + ((size_t)t_out * 4096 + n) * 64 + b) = o;
    }
  }
}

// ---------------- Phase 2: persistent recurrence ----------------
// Static LDS = 131072 + 8192 + 2048 = 141312 B. Regular launch, 64 WGs.
__global__ __launch_bounds__(256, 1) void lstm_rec(
    const u16* __restrict__ P, const float* __restrict__ c0,
    const float* __restrict__ Whh, u16* __restrict__ ring,
    float* __restrict__ out, int* __restrict__ seqb)
{
  __shared__ u16 Ws[64 * 1024];   // W_hh slice, XOR-swizzled
  __shared__ u16 GXb[4096];       // bf16 gate exchange (8KB)
  __shared__ u16 HXs[1024];       // h staging (2KB, intra-wave exchange)

  const int tid = threadIdx.x;
  const int lane = tid & 63;
  const int wid = tid >> 6;
  const int wg = blockIdx.x;

  // one-time W_hh slice -> LDS (bf16, XOR-swizzled rows)  [R17 verbatim]
  {
    const int rowp = tid >> 2;
    const int q = tid & 3;
    const int grow = (rowp >> 4) * 1024 + wg * 16 + (rowp & 15);
    const float4* src = (const float4*)(Whh + (size_t)grow * 1024 + q * 256);
    #pragma unroll 2
    for (int j = 0; j < 32; ++j) {
      float4 v0 = src[j * 2];
      float4 v1 = src[j * 2 + 1];
      short8 pk;
      pk[0] = (short)f2bf(v0.x); pk[1] = (short)f2bf(v0.y);
      pk[2] = (short)f2bf(v0.z); pk[3] = (short)f2bf(v0.w);
      pk[4] = (short)f2bf(v1.x); pk[5] = (short)f2bf(v1.y);
      pk[6] = (short)f2bf(v1.z); pk[7] = (short)f2bf(v1.w);
      const int kc = q * 32 + j;
      *(short8*)((char*)Ws + rowp * 2048 + ((kc ^ (rowp & 7)) << 4)) = pk;
    }
  }

  // pointwise role: unit u, batches b0..b0+3  [R17 verbatim]
  const int u = tid & 15;
  const int b0 = (tid >> 4) << 2;
  const int jh = wg * 16 + u;
  float cs[4];
  #pragma unroll
  for (int r = 0; r < 4; ++r) cs[r] = c0[(size_t)(b0 + r) * 1024 + jh];

  const int wm = wid & 1;
  const int wn = wid >> 1;
  const int kpos = lane >> 4;    // 0..3: k-subposition within a 32-unit K-slice
  const int flid = lane & 15;    // seq-word lane id

  __syncthreads();

  // blocked-layout A-fragment loads  [R17 verbatim]
  #define ISSUE_Q(buf, qi) {                                                   \
    const u16* bq_ = pA + (size_t)(qi) * 16384;                                \
    _Pragma("unroll")                                                          \
    for (int kq_ = 0; kq_ < 8; ++kq_) {                                        \
      const u16* pk_ = bq_ + kq_ * 2048;                                       \
      ISSUE_LD16C(buf[kq_][0], pk_, 0);                                        \
      ISSUE_LD16C(buf[kq_][1], pk_, 512);                                      \
    } }

  #define MFMA_Q(buf, qi) {                                                    \
    _Pragma("unroll")                                                          \
    for (int kq_ = 0; kq_ < 8; ++kq_) {                                        \
      const int kabs_ = (qi) * 8 + kq_;                                        \
      _Pragma("unroll")                                                        \
      for (int ni_ = 0; ni_ < 2; ++ni_) {                                      \
        const int rs_ = wn * 32 + ni_ * 16 + (lane & 15);                      \
        const int kcl_ = kabs_ * 4 + (lane >> 4);                              \
        const short8 bfr_ = *(const short8*)((const char*)Ws + rs_ * 2048      \
                            + ((kcl_ ^ (rs_ & 7)) << 4));                      \
        acc[0][ni_] = __builtin_amdgcn_mfma_f32_16x16x32_bf16(buf[kq_][0], bfr_, acc[0][ni_], 0, 0, 0); \
        acc[1][ni_] = __builtin_amdgcn_mfma_f32_16x16x32_bf16(buf[kq_][1], bfr_, acc[1][ni_], 0, 0, 0); \
      } } }

  for (int si = 0; si < 256; ++si) {
    const int t = 255 - si;
    const int lim = si;             // seq value required for this step's h
    const u16* rb = ring + (size_t)si * 65536;

    // blocked-layout per-lane base  [R17 verbatim]
    const u16* pA = rb + (size_t)(kpos >> 1) * 1024 + (kpos & 1) * 8
                    + (wm * 32 + (lane & 15)) * 16;

    // seq snapshot (oldest), then P loads (newest-4)
    int f0, f1, f2, f3;
    CHK_ISSUE(f0, 0); CHK_ISSUE(f1, 1); CHK_ISSUE(f2, 2); CHK_ISSUE(f3, 3);
    const size_t pbase = (size_t)t * 262144;
    unsigned long long Pi, Pf, Pg, Po;
    LD8_PLAIN(Pi, P + pbase + (size_t)(0 * 1024 + jh) * 64 + b0);
    LD8_PLAIN(Pf, P + pbase + (size_t)(1 * 1024 + jh) * 64 + b0);
    LD8_PLAIN(Pg, P + pbase + (size_t)(2 * 1024 + jh) * 64 + b0);
    LD8_PLAIN(Po, P + pbase + (size_t)(3 * 1024 + jh) * 64 + b0);
    WAIT_VMN(4);          // seq snapshot valid (P may be outstanding)

    f32x4 acc[2][2] = {};
    short8 afrA[8][2], afrB[8][2];

    // per-quarter gated counted pipeline (waits are younger-count invariant)
    SPIN_Q(f0, 0);
    ISSUE_Q(afrA, 0)
    SPIN_Q(f1, 1);
    ISSUE_Q(afrB, 1)
    WAIT_VMN(16); MFMA_Q(afrA, 0)    // P + q0 retired (q1 = newest 16)
    SPIN_Q(f2, 2);
    ISSUE_Q(afrA, 2)
    WAIT_VMN(16); MFMA_Q(afrB, 1)
    SPIN_Q(f3, 3);
    ISSUE_Q(afrB, 3)
    WAIT_VMN(16); MFMA_Q(afrA, 2)
    WAIT_VMN(0);  MFMA_Q(afrB, 3)

    // bf16 gate exchange through LDS (swizzled 8B stores)
    #pragma unroll
    for (int mi = 0; mi < 2; ++mi)
      #pragma unroll
      for (int ni = 0; ni < 2; ++ni) {
        const int g = wn * 2 + ni;
        const int uu = lane & 15;
        const int bb = wm * 32 + mi * 16 + ((lane >> 4) << 2);
        const f32x4 a = acc[mi][ni];
        u16x4 pk;
        pk[0] = f2bf(a[0]); pk[1] = f2bf(a[1]); pk[2] = f2bf(a[2]); pk[3] = f2bf(a[3]);
        *(u16x4*)((char*)GXb + ((((g * 16 + uu) * 64 + bb) << 1) ^ ((uu & 7) << 4))) = pk;
      }
    __syncthreads();

    const u16x4 vi = *(const u16x4*)((char*)GXb + ((((0 * 16 + u) * 64 + b0) << 1) ^ ((u & 7) << 4)));
    const u16x4 vf = *(const u16x4*)((char*)GXb + ((((1 * 16 + u) * 64 + b0) << 1) ^ ((u & 7) << 4)));
    const u16x4 vg = *(const u16x4*)((char*)GXb + ((((2 * 16 + u) * 64 + b0) << 1) ^ ((u & 7) << 4)));
    const u16x4 vo = *(const u16x4*)((char*)GXb + ((((3 * 16 + u) * 64 + b0) << 1) ^ ((u & 7) << 4)));

    float hvv[4], cnn[4];
    #pragma unroll
    for (int r = 0; r < 4; ++r) {
      const float xi = bf2f(vi[r]) + bf2f((u16)(Pi >> (16 * r)));
      const float xf = bf2f(vf[r]) + bf2f((u16)(Pf >> (16 * r)));
      const float xg = bf2f(vg[r]) + bf2f((u16)(Pg >> (16 * r)));
      const float xo = bf2f(vo[r]) + bf2f((u16)(Po >> (16 * r)));
      const float ig = sigm_fast(xi);
      const float fg = sigm_fast(xf);
      const float og = sigm_fast(xo);
      const float cn = fg * cs[r] + ig * tanhf(xg);
      const float hv = og * tanhf(cn);
      cs[r] = cn; cnn[r] = cn; hvv[r] = hv;
    }

    if (si < 255) {
      // h staging: HXs exchange is INTRA-WAVE (writer tid' shares bits[7:4]
      // with reader tid) -> lgkmcnt + sched_barrier suffice, no __syncthreads
      #pragma unroll
      for (int r = 0; r < 4; ++r) HXs[(b0 + r) * 16 + u] = f2bf(hvv[r]);
      asm volatile("s_waitcnt lgkmcnt(0)" ::: "memory");
      __builtin_amdgcn_sched_barrier(0);
      // BLOCKED publish: one contiguous 8B write-through store per thread
      {
        u16* wb = ring + (size_t)(si + 1) * 65536 + (size_t)wg * 1024;
        const unsigned long long hv8 = *(const unsigned long long*)(HXs + tid * 4);
        ST8_WT(wb + tid * 4, hv8);
      }
      WAIT_VMN(0);       // this wave's publish performed at MALL
      __syncthreads();   // whole WG drained (also covers GXb WAR for next step)
      // release: one 4B seq word per WG (no RMW, no same-line contention)
      if (tid == 0) ST4_WT(seqb + (wg << 5), si + 1);
      // ys stores fire-and-forget (acks retire under next step's waits)
      #pragma unroll
      for (int r = 0; r < 4; ++r)
        out[((size_t)t * 64 + b0 + r) * 1024 + jh] = hvv[r];
    } else {
      #pragma unroll
      for (int r = 0; r < 4; ++r) {
        out[((size_t)t * 64 + b0 + r) * 1024 + jh] = hvv[r];            // ys t=0
        out[YS_ELEMS + (size_t)(b0 + r) * 1024 + jh] = hvv[r];          // hT
        out[YS_ELEMS + 65536 + (size_t)(b0 + r) * 1024 + jh] = cnn[r];  // cT
      }
    }
  }
  #undef ISSUE_Q
  #undef MFMA_Q
}

// ---------------- launch ----------------
extern "C" void kernel_launch(void* const* d_in, const int* in_sizes, int n_in,
                              void* d_out, int out_size, void* d_ws, size_t ws_size,
                              hipStream_t stream) {
  const float* x   = (const float*)d_in[0];
  const float* h0  = (const float*)d_in[1];
  const float* c0  = (const float*)d_in[2];
  const float* Wih = (const float*)d_in[3];
  const float* Whh = (const float*)d_in[4];
  const float* bih = (const float*)d_in[5];
  const float* bhh = (const float*)d_in[6];
  float* out = (float*)d_out;

  char* ws = (char*)d_ws;
  u16* x_bf   = (u16*)(ws + 0);           // 32MB; recycled as h ring after gemm_pre
  u16* ring   = (u16*)(ws + 0);           // 256 x 131072 B (blocked layout)
  u16* wih_bf = (u16*)(ws + 33554432);
  u16* Pp     = (u16*)(ws + 41943040);    // 128MB
  int* seqb   = (int*)(ws + 176160768);   // 8KB (64 seq words, 128B-padded)

  hipLaunchKernelGGL(cast_f32_bf16, dim3(2048), dim3(256), 0, stream, x,   x_bf,   4194304);
  hipLaunchKernelGGL(cast_f32_bf16, dim3(1024), dim3(256), 0, stream, Wih, wih_bf, 1048576);
  hipLaunchKernelGGL(gemm_pre, dim3(128, 32), dim3(256), 0, stream, x_bf, wih_bf, bih, bhh, Pp);
  hipMemsetAsync(seqb, 0, 8192, stream);
  hipLaunchKernelGGL(scat_h0, dim3(32), dim3(256), 0, stream, h0, ring);
  hipLaunchKernelGGL(canary_k, dim3(1), dim3(1), 0, stream, out);

  // REGULAR launch (not cooperative): 64 WGs, 1/CU -> trivially co-resident.
  hipLaunchKernelGGL(lstm_rec, dim3(64), dim3(256), 0, stream,
                     (const u16*)Pp, c0, Whh, ring, out, seqb);
}